// Round 1
// baseline (1594.954 us; speedup 1.0000x reference)
//
#include <hip/hip_runtime.h>

typedef __attribute__((ext_vector_type(8))) short bf16x8;
typedef __attribute__((ext_vector_type(4))) float f32x4;
typedef __attribute__((ext_vector_type(4))) unsigned int u32x4;

constexpr int B_ = 4, L_ = 4096, S_ = 4096, D_ = 2048, H_ = 16, HD_ = 128;
constexpr int BM = 128, BN = 128, BK = 64, LDSS = BK + 8; // 72

__device__ __forceinline__ unsigned short f2bf(float f) {
    unsigned int u = __builtin_bit_cast(unsigned int, f);
    return (unsigned short)((u + 0x7fffu + ((u >> 16) & 1u)) >> 16);
}
__device__ __forceinline__ float bf2f(unsigned short h) {
    unsigned int u = ((unsigned int)h) << 16;
    return __builtin_bit_cast(float, u);
}
__device__ __forceinline__ unsigned long long pack4(float a, float b, float c, float d) {
    return (unsigned long long)f2bf(a) | ((unsigned long long)f2bf(b) << 16)
         | ((unsigned long long)f2bf(c) << 32) | ((unsigned long long)f2bf(d) << 48);
}
__device__ __forceinline__ float featmap(float x) {
    return x > 0.f ? x + 1.f : __expf(x);
}

// C = A @ B^T with A [M,K] row-major, B [N,K] row-major (weights are [out,in]).
// MODE 0: A=query(f32). bn<16 -> C1=q_feat=featmap(.); bn>=16 -> B=Bw2(Wg), C2=gate=sigmoid(.+bias)
// MODE 1: A=kv(f32), B=Wkv[4096,2048]. bn<16 -> k: featmap, TRANSPOSED store to C1[bh][d][s];
//         bn>=16 -> v: passthrough, transposed store to C2.
// MODE 2: A=Ah(bf16)=y, B=Wo, plain fp32 output Cf.
template<int MODE>
__global__ __launch_bounds__(256) void gemm_bt(
    const float* __restrict__ Af, const unsigned short* __restrict__ Ah,
    const float* __restrict__ Bw, const float* __restrict__ Bw2,
    unsigned short* __restrict__ C1, unsigned short* __restrict__ C2,
    float* __restrict__ Cf, const float* __restrict__ bias)
{
    __shared__ unsigned short smem[BM * LDSS + BN * LDSS];
    unsigned short* As = smem;
    unsigned short* Bs = smem + BM * LDSS;
    const int tid = threadIdx.x;
    const int bm = blockIdx.x, bn = blockIdx.y;
    const int row0 = bm * BM;
    const int lane = tid & 63, w = tid >> 6;
    const int wm = (w >> 1) * 64, wn = (w & 1) * 64;
    const int lr = lane & 15, lk = (lane >> 4) * 8;
    const bool second = bn >= H_;
    const float* Bp = (MODE == 0 && second) ? Bw2 : Bw;
    const int bcol = (MODE == 0 && second) ? (bn - H_) * BN : bn * BN;

    f32x4 acc[4][4] = {};

    for (int k0 = 0; k0 < D_; k0 += BK) {
        if (MODE == 2) {
            #pragma unroll
            for (int i = 0; i < 4; i++) {
                int idx = tid + i * 256;
                int r = idx >> 3, c = (idx & 7) * 8;
                *(u32x4*)&As[r * LDSS + c] =
                    *(const u32x4*)&Ah[(size_t)(row0 + r) * D_ + k0 + c];
            }
        } else {
            #pragma unroll
            for (int i = 0; i < 8; i++) {
                int idx = tid + i * 256;
                int r = idx >> 4, c = (idx & 15) * 4;
                const float4 v = *(const float4*)&Af[(size_t)(row0 + r) * D_ + k0 + c];
                *(unsigned long long*)&As[r * LDSS + c] = pack4(v.x, v.y, v.z, v.w);
            }
        }
        #pragma unroll
        for (int i = 0; i < 8; i++) {
            int idx = tid + i * 256;
            int r = idx >> 4, c = (idx & 15) * 4;
            const float4 v = *(const float4*)&Bp[(size_t)(bcol + r) * D_ + k0 + c];
            *(unsigned long long*)&Bs[r * LDSS + c] = pack4(v.x, v.y, v.z, v.w);
        }
        __syncthreads();
        #pragma unroll
        for (int ks = 0; ks < BK; ks += 32) {
            bf16x8 av[4], bv[4];
            #pragma unroll
            for (int mi = 0; mi < 4; mi++)
                av[mi] = *(const bf16x8*)&As[(wm + mi * 16 + lr) * LDSS + ks + lk];
            #pragma unroll
            for (int ni = 0; ni < 4; ni++)
                bv[ni] = *(const bf16x8*)&Bs[(wn + ni * 16 + lr) * LDSS + ks + lk];
            #pragma unroll
            for (int mi = 0; mi < 4; mi++)
                #pragma unroll
                for (int ni = 0; ni < 4; ni++)
                    acc[mi][ni] = __builtin_amdgcn_mfma_f32_16x16x32_bf16(
                        av[mi], bv[ni], acc[mi][ni], 0, 0, 0);
        }
        __syncthreads();
    }

    const int rb = (lane >> 4) * 4;
    if (MODE == 1) {
        // transpose 128x128 tile through LDS, write [bh][d][s] coalesced
        unsigned short* TT = smem;          // 128*136 = 17408 <= 18432 (reuse As+Bs)
        const int TP = HD_ + 8;             // 136
        const int isv = second ? 1 : 0;
        const int h2 = bn & (H_ - 1);
        #pragma unroll
        for (int mi = 0; mi < 4; mi++) {
            #pragma unroll
            for (int ni = 0; ni < 4; ni++) {
                float x0 = acc[mi][ni][0], x1 = acc[mi][ni][1];
                float x2 = acc[mi][ni][2], x3 = acc[mi][ni][3];
                if (!isv) {
                    x0 = featmap(x0); x1 = featmap(x1);
                    x2 = featmap(x2); x3 = featmap(x3);
                }
                *(unsigned long long*)&TT[(wn + ni * 16 + lr) * TP + wm + mi * 16 + rb]
                    = pack4(x0, x1, x2, x3);
            }
        }
        __syncthreads();
        const int b = row0 >> 12;           // 4096 rows per batch
        const int sl0 = row0 & (S_ - 1);
        unsigned short* dst = (isv ? C2 : C1) + (size_t)(b * H_ + h2) * HD_ * S_;
        #pragma unroll
        for (int i = 0; i < 8; i++) {
            int idx = tid + 256 * i;
            int d = idx >> 4, sc = (idx & 15) * 8;
            *(u32x4*)&dst[(size_t)d * S_ + sl0 + sc] = *(const u32x4*)&TT[d * TP + sc];
        }
        return;
    }
    #pragma unroll
    for (int mi = 0; mi < 4; mi++) {
        #pragma unroll
        for (int ni = 0; ni < 4; ni++) {
            #pragma unroll
            for (int r = 0; r < 4; r++) {
                const size_t gr = (size_t)(row0 + wm + mi * 16 + rb + r);
                const int gc = bcol + wn + ni * 16 + lr;
                float x = acc[mi][ni][r];
                if (MODE == 0) {
                    if (!second) {
                        C1[gr * D_ + gc] = f2bf(featmap(x));
                    } else {
                        float t = x + bias[gc];
                        C2[gr * D_ + gc] = f2bf(1.f / (1.f + __expf(-t)));
                    }
                } else {
                    Cf[gr * D_ + gc] = x;
                }
            }
        }
    }
}

// kv_summary partials: per (s-chunk cx, bh): part[cx][bh][d][e] = sum_{s in chunk} k[s,d]*v[s,e]
// inputs are transposed [bh][d][s] so LDS staging is fully vectorized.
__global__ __launch_bounds__(256) void kvsum_part(
    const unsigned short* __restrict__ kT, const unsigned short* __restrict__ vT,
    float* __restrict__ part, float* __restrict__ ksum_part)
{
    __shared__ unsigned short kA[HD_ * LDSS];
    __shared__ unsigned short vB[HD_ * LDSS];
    __shared__ float red[HD_ * 8];
    const int tid = threadIdx.x;
    const int cx = blockIdx.x, bh = blockIdx.y;
    const int lane = tid & 63, w = tid >> 6;
    const int wm = (w >> 1) * 64, wn = (w & 1) * 64;
    const int lr = lane & 15, lk = (lane >> 4) * 8;
    const unsigned short* kb = kT + (size_t)bh * HD_ * S_;
    const unsigned short* vb = vT + (size_t)bh * HD_ * S_;
    f32x4 acc[4][4] = {};
    float ksl[4] = {0.f, 0.f, 0.f, 0.f};
    const int chunk = S_ / 8;
    const int s_begin = cx * chunk;
    for (int s0 = s_begin; s0 < s_begin + chunk; s0 += 64) {
        #pragma unroll
        for (int i = 0; i < 4; i++) {
            int idx = tid + i * 256;
            int d = idx >> 3, sc = (idx & 7) * 8;
            u32x4 kk = *(const u32x4*)&kb[(size_t)d * S_ + s0 + sc];
            *(u32x4*)&kA[d * LDSS + sc] = kk;
            unsigned short t8[8];
            *(u32x4*)t8 = kk;
            float ss = 0.f;
            #pragma unroll
            for (int j = 0; j < 8; j++) ss += bf2f(t8[j]);
            ksl[i] += ss;
            *(u32x4*)&vB[d * LDSS + sc] = *(const u32x4*)&vb[(size_t)d * S_ + s0 + sc];
        }
        __syncthreads();
        #pragma unroll
        for (int ks = 0; ks < 64; ks += 32) {
            bf16x8 av[4], bv[4];
            #pragma unroll
            for (int mi = 0; mi < 4; mi++)
                av[mi] = *(const bf16x8*)&kA[(wm + mi * 16 + lr) * LDSS + ks + lk];
            #pragma unroll
            for (int ni = 0; ni < 4; ni++)
                bv[ni] = *(const bf16x8*)&vB[(wn + ni * 16 + lr) * LDSS + ks + lk];
            #pragma unroll
            for (int mi = 0; mi < 4; mi++)
                #pragma unroll
                for (int ni = 0; ni < 4; ni++)
                    acc[mi][ni] = __builtin_amdgcn_mfma_f32_16x16x32_bf16(
                        av[mi], bv[ni], acc[mi][ni], 0, 0, 0);
        }
        __syncthreads();
    }
    // k_sum partial: thread covered d = tid>>3 + 32*i, 8 s-values per stage
    #pragma unroll
    for (int i = 0; i < 4; i++) red[((tid >> 3) + 32 * i) * 8 + (tid & 7)] = ksl[i];
    __syncthreads();
    if (tid < HD_) {
        float s = 0.f;
        #pragma unroll
        for (int j = 0; j < 8; j++) s += red[tid * 8 + j];
        ksum_part[(size_t)cx * (64 * HD_) + bh * HD_ + tid] = s;
    }
    const int rb = (lane >> 4) * 4;
    float* pp = part + ((size_t)cx * 64 + bh) * (HD_ * HD_);
    #pragma unroll
    for (int mi = 0; mi < 4; mi++)
        #pragma unroll
        for (int ni = 0; ni < 4; ni++)
            #pragma unroll
            for (int r = 0; r < 4; r++)
                pp[(wm + mi * 16 + rb + r) * HD_ + wn + ni * 16 + lr] = acc[mi][ni][r];
}

// reduce 8 partials -> kvsT[bh][e][d] (bf16, transposed so attn B-frags are contiguous) + ksum
__global__ __launch_bounds__(256) void kvs_reduce(
    const float* __restrict__ part, unsigned short* __restrict__ kvsT,
    const float* __restrict__ ksum_part, float* __restrict__ ksum)
{
    const int idx = blockIdx.x * 256 + threadIdx.x;
    const int e = idx & 127, d2 = (idx >> 7) & 127, bh = idx >> 14;
    float s = 0.f;
    #pragma unroll
    for (int cx = 0; cx < 8; cx++)
        s += part[((size_t)cx * 64 + bh) * 16384 + d2 * 128 + e];
    kvsT[((size_t)bh * 128 + e) * 128 + d2] = f2bf(s);
    if (idx < 64 * 128) {
        float t = 0.f;
        #pragma unroll
        for (int cx = 0; cx < 8; cx++) t += ksum_part[cx * 8192 + idx];
        ksum[idx] = t;
    }
}

// attn = (q @ kvs) * z * gate -> y (bf16)
__global__ __launch_bounds__(256) void attn_kernel(
    const unsigned short* __restrict__ qf, const unsigned short* __restrict__ kvsT,
    const float* __restrict__ ksum, const unsigned short* __restrict__ gate,
    unsigned short* __restrict__ y)
{
    __shared__ unsigned short qs[128 * 136];
    __shared__ unsigned short bs[128 * LDSS];
    __shared__ float zl[128];
    const int tid = threadIdx.x;
    const int l0 = blockIdx.x * 128;
    const int h = blockIdx.y, b = blockIdx.z;
    const int bh = b * H_ + h;
    const int lane = tid & 63, w = tid >> 6;
    const int wm = (w >> 1) * 64, wn = (w & 1) * 64;
    const int lr = lane & 15, lk = (lane >> 4) * 8;
    const size_t qbase = (size_t)b * L_ * D_ + (size_t)h * HD_;
    #pragma unroll
    for (int i = 0; i < 8; i++) {
        int idx = tid + i * 256;
        int r = idx >> 4, c = (idx & 15) * 8;
        *(u32x4*)&qs[r * 136 + c] = *(const u32x4*)&qf[qbase + (size_t)(l0 + r) * D_ + c];
    }
    __syncthreads();
    if (tid < 128) {
        const float* kp = ksum + bh * HD_;
        float sden = 0.f;
        #pragma unroll 4
        for (int d2 = 0; d2 < HD_; d2++) sden += bf2f(qs[tid * 136 + d2]) * kp[d2];
        zl[tid] = 1.f / (sden + 1e-6f);
    }
    f32x4 acc[4][4] = {};
    for (int kc = 0; kc < 2; kc++) {
        #pragma unroll
        for (int i = 0; i < 4; i++) {
            int idx = tid + i * 256;
            int e = idx >> 3, dc = (idx & 7) * 8;
            *(u32x4*)&bs[e * LDSS + dc] =
                *(const u32x4*)&kvsT[((size_t)bh * 128 + e) * 128 + kc * 64 + dc];
        }
        __syncthreads();
        #pragma unroll
        for (int ks = 0; ks < 64; ks += 32) {
            bf16x8 av[4], bv[4];
            #pragma unroll
            for (int mi = 0; mi < 4; mi++)
                av[mi] = *(const bf16x8*)&qs[(wm + mi * 16 + lr) * 136 + kc * 64 + ks + lk];
            #pragma unroll
            for (int ni = 0; ni < 4; ni++)
                bv[ni] = *(const bf16x8*)&bs[(wn + ni * 16 + lr) * LDSS + ks + lk];
            #pragma unroll
            for (int mi = 0; mi < 4; mi++)
                #pragma unroll
                for (int ni = 0; ni < 4; ni++)
                    acc[mi][ni] = __builtin_amdgcn_mfma_f32_16x16x32_bf16(
                        av[mi], bv[ni], acc[mi][ni], 0, 0, 0);
        }
        __syncthreads();
    }
    const int rb = (lane >> 4) * 4;
    #pragma unroll
    for (int mi = 0; mi < 4; mi++) {
        #pragma unroll
        for (int ni = 0; ni < 4; ni++) {
            #pragma unroll
            for (int r = 0; r < 4; r++) {
                int ll = wm + mi * 16 + rb + r;
                int e = wn + ni * 16 + lr;
                float attn = acc[mi][ni][r] * zl[ll];
                float g = bf2f(gate[qbase + (size_t)(l0 + ll) * D_ + e]);
                y[qbase + (size_t)(l0 + ll) * D_ + e] = f2bf(attn * g);
            }
        }
    }
}

extern "C" void kernel_launch(void* const* d_in, const int* in_sizes, int n_in,
                              void* d_out, int out_size, void* d_ws, size_t ws_size,
                              hipStream_t stream)
{
    (void)in_sizes; (void)n_in; (void)out_size; (void)ws_size;
    const float* query = (const float*)d_in[0];
    const float* kv    = (const float*)d_in[1];
    const float* Wq    = (const float*)d_in[2];
    const float* Wg    = (const float*)d_in[3];
    const float* bg    = (const float*)d_in[4];
    const float* Wkv   = (const float*)d_in[5];
    const float* Wo    = (const float*)d_in[6];
    float* out = (float*)d_out;
    char* ws = (char*)d_ws;

    // workspace layout (bytes)
    unsigned short* q_feat    = (unsigned short*)(ws);                 // 64 MiB
    unsigned short* gate      = (unsigned short*)(ws + 67108864);      // 64 MiB
    unsigned short* kTb       = (unsigned short*)(ws + 134217728);     // 64 MiB [bh][d][s]
    unsigned short* vTb       = (unsigned short*)(ws + 201326592);     // 64 MiB [bh][d][s]
    float*          part      = (float*)(ws + 268435456);              // 32 MiB
    float*          ksum_part = (float*)(ws + 301989888);              // 256 KiB
    float*          ksum      = (float*)(ws + 302252032);              // 32 KiB
    unsigned short* kvsT      = (unsigned short*)(ws + 302284800);     // 2 MiB [bh][e][d]
    unsigned short* ybuf      = kTb;  // kT dead after kvsum_part; reuse for y

    dim3 blk(256, 1, 1);
    // q_feat + gate
    gemm_bt<0><<<dim3(128, 32), blk, 0, stream>>>(query, nullptr, Wq, Wg,
                                                  q_feat, gate, nullptr, bg);
    // k_feat^T, v^T
    gemm_bt<1><<<dim3(128, 32), blk, 0, stream>>>(kv, nullptr, Wkv, nullptr,
                                                  kTb, vTb, nullptr, nullptr);
    // kv_summary partials + ksum partials
    kvsum_part<<<dim3(8, 64), blk, 0, stream>>>(kTb, vTb, part, ksum_part);
    kvs_reduce<<<dim3(4096), blk, 0, stream>>>(part, kvsT, ksum_part, ksum);
    // attn * z * gate -> y
    attn_kernel<<<dim3(32, 16, 4), blk, 0, stream>>>(q_feat, kvsT, ksum, gate, ybuf);
    // out = y @ Wo^T
    gemm_bt<2><<<dim3(128, 16), blk, 0, stream>>>(nullptr, ybuf, Wo, nullptr,
                                                  nullptr, nullptr, out, nullptr);
}